// Round 3
// baseline (113.626 us; speedup 1.0000x reference)
//
#include <hip/hip_runtime.h>
#include <hip/hip_bf16.h>

#define IN_F 8192
#define OUT_F 8192
#define NROWS 128
#define CB 256

using bf8   = __attribute__((ext_vector_type(8))) short;  // 8 bf16 (4 VGPRs)
using f32x4 = __attribute__((ext_vector_type(4))) float;  // 4 fp32 accum

__device__ inline unsigned short f2bf(float f) {
    __hip_bfloat16 h = __float2bfloat16(f);
    return *reinterpret_cast<unsigned short*>(&h);
}

// ---------------- Kernel A: x = fwht(input/scaleWH*SU), store bf16 ----------
__global__ __launch_bounds__(512) void k_pre(const float* __restrict__ in,
                                             const float* __restrict__ scaleWH,
                                             const float* __restrict__ SU,
                                             unsigned short* __restrict__ xpre) {
    __shared__ float row[IN_F];
    const int r = blockIdx.x;
    const float4* src = reinterpret_cast<const float4*>(in + (size_t)r * IN_F);
    const float4* sc  = reinterpret_cast<const float4*>(scaleWH);
    const float4* su  = reinterpret_cast<const float4*>(SU);
    for (int c = threadIdx.x; c < IN_F / 4; c += 512) {
        float4 x = src[c], s = sc[c], u = su[c];
        row[c * 4 + 0] = x.x / s.x * u.x;
        row[c * 4 + 1] = x.y / s.y * u.y;
        row[c * 4 + 2] = x.z / s.z * u.z;
        row[c * 4 + 3] = x.w / s.w * u.w;
    }
    __syncthreads();
#pragma unroll 1
    for (int s = 0; s < 13; ++s) {
        const int h = 1 << s;
        for (int p = threadIdx.x; p < IN_F / 2; p += 512) {
            const int i = ((p >> s) << (s + 1)) | (p & (h - 1));
            const int j = i + h;
            float a = row[i], b = row[j];
            row[i] = a + b;
            row[j] = a - b;
        }
        __syncthreads();
    }
    const float scale = 0.011048543456039806f;  // 1/sqrt(8192)
    uint4* dst = reinterpret_cast<uint4*>(xpre + (size_t)r * IN_F);
    for (int c = threadIdx.x; c < IN_F / 8; c += 512) {
        unsigned int w[4];
#pragma unroll
        for (int q = 0; q < 4; ++q) {
            unsigned int lo = f2bf(row[c * 8 + 2 * q]     * scale);
            unsigned int hi = f2bf(row[c * 8 + 2 * q + 1] * scale);
            w[q] = lo | (hi << 16);
        }
        dst[c] = make_uint4(w[0], w[1], w[2], w[3]);
    }
}

// ---------------- Kernel B: out1 = xpre @ W_hat^T (dequant on the fly) ------
#define NT 32   // n-tile per workgroup
#define KC 64   // k-chunk
__global__ __launch_bounds__(256) void k_gemm(const unsigned short* __restrict__ xpre,
                                              const int* __restrict__ Qidxs,
                                              const float* __restrict__ cb,
                                              const float* __restrict__ wscale,
                                              float* __restrict__ out1) {
    __shared__ __align__(16) unsigned short cbl[CB][8];     // codebook * Wscale, bf16
    __shared__ __align__(16) unsigned short At[NROWS][72];  // padded (72 = 64+8)
    __shared__ __align__(16) unsigned short Bt[NT][72];
    const int tid = threadIdx.x;
    const float ws = wscale[0];
    for (int e = tid; e < CB * 8; e += 256)
        cbl[e >> 3][e & 7] = f2bf(cb[e] * ws);

    const int n0 = blockIdx.x * NT;
    const int wave = tid >> 6, lane = tid & 63;
    const int lrow = lane & 15, lk8 = lane >> 4;
    f32x4 acc[2][2];
#pragma unroll
    for (int mt = 0; mt < 2; ++mt)
#pragma unroll
        for (int nt = 0; nt < 2; ++nt) acc[mt][nt] = (f32x4){0.f, 0.f, 0.f, 0.f};

    const int* qrow = Qidxs + (size_t)n0 * (IN_F / 8);
    const int bn = tid >> 3, bslot = tid & 7;     // B dequant: 1 idx/thread
    __syncthreads();

    for (int kc = 0; kc < IN_F; kc += KC) {
        // stage A tile 128x64 (bf16, 16B vector loads)
#pragma unroll
        for (int it = 0; it < 4; ++it) {
            const int c = tid + it * 256;
            const int rowi = c >> 3, col8 = c & 7;
            uint4 v = *reinterpret_cast<const uint4*>(xpre + (size_t)rowi * IN_F + kc + col8 * 8);
            *reinterpret_cast<uint4*>(&At[rowi][col8 * 8]) = v;
        }
        // dequant B tile 32x64: one int32 index -> 8 bf16 weights
        {
            const int idx = qrow[(size_t)bn * (IN_F / 8) + (kc >> 3) + bslot];
            uint4 w = *reinterpret_cast<const uint4*>(&cbl[idx][0]);
            *reinterpret_cast<uint4*>(&Bt[bn][bslot * 8]) = w;
        }
        __syncthreads();
#pragma unroll
        for (int kk = 0; kk < KC; kk += 32) {
            bf8 afrag[2], bfrag[2];
#pragma unroll
            for (int mt = 0; mt < 2; ++mt)
                afrag[mt] = *reinterpret_cast<const bf8*>(&At[wave * 32 + mt * 16 + lrow][kk + lk8 * 8]);
#pragma unroll
            for (int nt = 0; nt < 2; ++nt)
                bfrag[nt] = *reinterpret_cast<const bf8*>(&Bt[nt * 16 + lrow][kk + lk8 * 8]);
#pragma unroll
            for (int mt = 0; mt < 2; ++mt)
#pragma unroll
                for (int nt = 0; nt < 2; ++nt)
                    acc[mt][nt] = __builtin_amdgcn_mfma_f32_16x16x32_bf16(
                        afrag[mt], bfrag[nt], acc[mt][nt], 0, 0, 0);
        }
        __syncthreads();
    }
    // epilogue: D[row][col], col = lane&15, row = (lane>>4)*4 + reg; store f32
    const int m0 = wave * 32;
#pragma unroll
    for (int mt = 0; mt < 2; ++mt)
#pragma unroll
        for (int nt = 0; nt < 2; ++nt)
#pragma unroll
            for (int r = 0; r < 4; ++r) {
                const int row = m0 + mt * 16 + lk8 * 4 + r;
                const int col = n0 + nt * 16 + lrow;
                out1[(size_t)row * OUT_F + col] = acc[mt][nt][r];
            }
}

// ---------------- Kernel C: io = fwht(io)*SV + bias, in-place f32 -----------
__global__ __launch_bounds__(512) void k_post(float* __restrict__ io,
                                              const float* __restrict__ SV,
                                              const float* __restrict__ bias) {
    __shared__ float row[OUT_F];
    const int r = blockIdx.x;
    float4* rp = reinterpret_cast<float4*>(io + (size_t)r * OUT_F);
    for (int c = threadIdx.x; c < OUT_F / 4; c += 512) {
        float4 v = rp[c];
        row[c * 4 + 0] = v.x; row[c * 4 + 1] = v.y;
        row[c * 4 + 2] = v.z; row[c * 4 + 3] = v.w;
    }
    __syncthreads();
#pragma unroll 1
    for (int s = 0; s < 13; ++s) {
        const int h = 1 << s;
        for (int p = threadIdx.x; p < OUT_F / 2; p += 512) {
            const int i = ((p >> s) << (s + 1)) | (p & (h - 1));
            const int j = i + h;
            float a = row[i], b = row[j];
            row[i] = a + b;
            row[j] = a - b;
        }
        __syncthreads();
    }
    const float scale = 0.011048543456039806f;  // 1/sqrt(8192)
    const float4* svp = reinterpret_cast<const float4*>(SV);
    const float4* bip = reinterpret_cast<const float4*>(bias);
    for (int c = threadIdx.x; c < OUT_F / 4; c += 512) {
        float4 sv = svp[c], bi = bip[c], o;
        o.x = row[c * 4 + 0] * scale * sv.x + bi.x;
        o.y = row[c * 4 + 1] * scale * sv.y + bi.y;
        o.z = row[c * 4 + 2] * scale * sv.z + bi.z;
        o.w = row[c * 4 + 3] * scale * sv.w + bi.w;
        rp[c] = o;
    }
}

extern "C" void kernel_launch(void* const* d_in, const int* in_sizes, int n_in,
                              void* d_out, int out_size, void* d_ws, size_t ws_size,
                              hipStream_t stream) {
    const float* in      = (const float*)d_in[0];
    const int*   Qidxs   = (const int*)d_in[1];
    const float* cb      = (const float*)d_in[2];
    const float* scaleWH = (const float*)d_in[3];
    const float* SU      = (const float*)d_in[4];
    const float* SV      = (const float*)d_in[5];
    const float* wscale  = (const float*)d_in[6];
    const float* bias    = (const float*)d_in[7];
    float* out = (float*)d_out;

    unsigned short* xpre = (unsigned short*)d_ws;   // 2 MB bf16 in workspace

    k_pre<<<NROWS, 512, 0, stream>>>(in, scaleWH, SU, xpre);
    k_gemm<<<OUT_F / NT, 256, 0, stream>>>(xpre, Qidxs, cb, wscale, out);
    k_post<<<NROWS, 512, 0, stream>>>(out, SV, bias);
}

// Round 4
// 69.226 us; speedup vs baseline: 1.6414x; 1.6414x over previous
//
#include <hip/hip_runtime.h>
#include <hip/hip_bf16.h>

#define IN_F 8192
#define OUT_F 8192
#define NROWS 128
#define CB 256
#define NSL 8                  // split-K slices
#define KSLICE (IN_F / NSL)    // 1024
#define KC 64                  // k-chunk staged per iteration

using bf8   = __attribute__((ext_vector_type(8))) short;  // 8 bf16 (4 VGPRs)
using f32x4 = __attribute__((ext_vector_type(4))) float;  // 4 fp32 accum

typedef const __attribute__((address_space(1))) void* as1cv;
typedef __attribute__((address_space(3))) void* as3v;

__device__ inline float bf2f(unsigned int u) {
    union { unsigned int i; float f; } v; v.i = u << 16; return v.f;
}
__device__ inline unsigned short f2bf(float f) {
    __hip_bfloat16 h = __float2bfloat16(f);
    return *reinterpret_cast<unsigned short*>(&h);
}
__device__ inline void unpack8(uint4 v, float* f) {
    f[0] = bf2f(v.x & 0xffffu); f[1] = bf2f(v.x >> 16);
    f[2] = bf2f(v.y & 0xffffu); f[3] = bf2f(v.y >> 16);
    f[4] = bf2f(v.z & 0xffffu); f[5] = bf2f(v.z >> 16);
    f[6] = bf2f(v.w & 0xffffu); f[7] = bf2f(v.w >> 16);
}

#define FWHT_SCALE 0.011048543456039806f  // 1/sqrt(8192)

// ================= NEW PATH =================

// ---- Kernel A: xpre = fwht(input/scaleWH*SU)  [bf16 out] ----
// 512 threads, 16 elems/thread: 4 in-register stages + 9 LDS stages.
__global__ __launch_bounds__(512) void k_pre_new(const float* __restrict__ in,
                                                 const float* __restrict__ scaleWH,
                                                 const float* __restrict__ SU,
                                                 unsigned short* __restrict__ xpre) {
    __shared__ float row[IN_F];
    const int r = blockIdx.x, t = threadIdx.x;
    float v[16];
    const float4* xp = reinterpret_cast<const float4*>(in + (size_t)r * IN_F);
    const float4* sp = reinterpret_cast<const float4*>(scaleWH);
    const float4* up = reinterpret_cast<const float4*>(SU);
#pragma unroll
    for (int q = 0; q < 4; ++q) {
        float4 x = xp[t * 4 + q], s = sp[t * 4 + q], u = up[t * 4 + q];
        v[q * 4 + 0] = x.x / s.x * u.x;
        v[q * 4 + 1] = x.y / s.y * u.y;
        v[q * 4 + 2] = x.z / s.z * u.z;
        v[q * 4 + 3] = x.w / s.w * u.w;
    }
#pragma unroll
    for (int s = 0; s < 4; ++s) {
        const int h = 1 << s;
#pragma unroll
        for (int j = 0; j < 16; ++j)
            if (!(j & h)) { float a = v[j], b = v[j | h]; v[j] = a + b; v[j | h] = a - b; }
    }
#pragma unroll
    for (int q = 0; q < 4; ++q)
        reinterpret_cast<float4*>(row)[t * 4 + q] =
            make_float4(v[q * 4 + 0], v[q * 4 + 1], v[q * 4 + 2], v[q * 4 + 3]);
    __syncthreads();
#pragma unroll 1
    for (int s = 4; s < 13; ++s) {
        const int h = 1 << s;
        for (int p = t; p < IN_F / 2; p += 512) {
            const int i = ((p >> s) << (s + 1)) | (p & (h - 1));
            const int j = i + h;
            float a = row[i], b = row[j];
            row[i] = a + b; row[j] = a - b;
        }
        __syncthreads();
    }
    uint4* dst = reinterpret_cast<uint4*>(xpre + (size_t)r * IN_F);
#pragma unroll
    for (int half = 0; half < 2; ++half) {
        unsigned int w[4];
#pragma unroll
        for (int q = 0; q < 4; ++q) {
            float f0 = row[t * 16 + half * 8 + 2 * q]     * FWHT_SCALE;
            float f1 = row[t * 16 + half * 8 + 2 * q + 1] * FWHT_SCALE;
            w[q] = (unsigned int)f2bf(f0) | ((unsigned int)f2bf(f1) << 16);
        }
        dst[t * 2 + half] = make_uint4(w[0], w[1], w[2], w[3]);
    }
}

// ---- Kernel B: bf16 partial GEMM slices, direct-codebook B fragments ----
// grid (64, NSL); 256 thr = 4 waves (2 wave-rows x 2 wave-cols); tile 128x128.
__global__ __launch_bounds__(256, 3) void k_gemm_new(
        const unsigned short* __restrict__ xpre,
        const int* __restrict__ Qidxs,
        const float* __restrict__ cb,
        const float* __restrict__ wscale,
        unsigned short* __restrict__ pout) {
    __shared__ __align__(16) unsigned short cbl[CB][8];
    __shared__ __align__(16) unsigned short At[2][NROWS * KC];   // linear, XOR-swizzled
    const int tid = threadIdx.x;
    const int wave = tid >> 6, lane = tid & 63;
    const int wr = wave >> 1, wc = wave & 1;
    const int lr = lane & 15, lk8 = lane >> 4;
    const int row_in = lane >> 3, slot = lane & 7;   // staging decomposition
    const int n0 = blockIdx.x * 128;
    const int ks0 = blockIdx.y * KSLICE;

    // stage: At[buf] holds rows 0..127 x KC cols; element (row, oct) at byte
    //   row*128 + ((oct ^ (row&7))<<4). global_load_lds dest is linear
    //   (wave-uniform base + lane*16); source is pre-swizzled per lane.
    auto stage = [&](int buf, int kc) {
#pragma unroll
        for (int i = 0; i < 4; ++i) {
            const int srow = wave * 32 + i * 8 + row_in;
            const unsigned short* g = xpre + (size_t)srow * IN_F + ks0 + kc
                                      + ((slot ^ row_in) << 3);
            as3v l = (as3v)(At[buf] + (wave * 32 + i * 8) * KC);
            __builtin_amdgcn_global_load_lds((as1cv)(const void*)g, l, 16, 0, 0);
        }
    };
    stage(0, 0);
    const float wsc = wscale[0];
    for (int e = tid; e < CB * 8; e += 256) cbl[e >> 3][e & 7] = f2bf(cb[e] * wsc);

    f32x4 acc[4][4];
#pragma unroll
    for (int mt = 0; mt < 4; ++mt)
#pragma unroll
        for (int nt = 0; nt < 4; ++nt) acc[mt][nt] = (f32x4){0.f, 0.f, 0.f, 0.f};

    const int* qbase = Qidxs + (size_t)(n0 + wc * 64 + lr) * (IN_F / 8) + ks0 / 8;
    __syncthreads();

    int buf = 0;
#pragma unroll 1
    for (int it = 0; it < KSLICE / KC; ++it) {
        const int kc = it * KC;
        if (it + 1 < KSLICE / KC) stage(buf ^ 1, kc + KC);
        const char* Ab = (const char*)At[buf];
#pragma unroll
        for (int kk = 0; kk < KC; kk += 32) {
            const int colq = ((kc + kk) >> 3) + lk8;
            int idxv[4];
#pragma unroll
            for (int nt = 0; nt < 4; ++nt) idxv[nt] = qbase[nt * 16 * (IN_F / 8) + colq];
            bf8 bfr[4], afr[4];
#pragma unroll
            for (int nt = 0; nt < 4; ++nt) bfr[nt] = *(const bf8*)&cbl[idxv[nt]][0];
            const int octx = ((kk >> 3) + lk8) ^ (lr & 7);
#pragma unroll
            for (int mt = 0; mt < 4; ++mt) {
                const int rowm = wr * 64 + mt * 16 + lr;
                afr[mt] = *(const bf8*)(Ab + rowm * (KC * 2) + (octx << 4));
            }
#pragma unroll
            for (int mt = 0; mt < 4; ++mt)
#pragma unroll
                for (int nt = 0; nt < 4; ++nt)
                    acc[mt][nt] = __builtin_amdgcn_mfma_f32_16x16x32_bf16(
                        afr[mt], bfr[nt], acc[mt][nt], 0, 0, 0);
        }
        __syncthreads();
        buf ^= 1;
    }
    // epilogue: C/D col=lane&15, row=(lane>>4)*4+reg; bf16 partial store
    unsigned short* ps = pout + (size_t)blockIdx.y * (NROWS * OUT_F);
#pragma unroll
    for (int mt = 0; mt < 4; ++mt) {
        const int row = wr * 64 + mt * 16 + lk8 * 4;
#pragma unroll
        for (int nt = 0; nt < 4; ++nt) {
            const int col = n0 + wc * 64 + nt * 16 + lr;
#pragma unroll
            for (int r2 = 0; r2 < 4; ++r2)
                ps[(size_t)(row + r2) * OUT_F + col] = f2bf(acc[mt][nt][r2]);
        }
    }
}

// ---- Kernel C: out = fwht(sum_slices)*SV + bias  [f32 out] ----
__global__ __launch_bounds__(512) void k_post_new(const unsigned short* __restrict__ pin,
                                                  const float* __restrict__ SV,
                                                  const float* __restrict__ bias,
                                                  float* __restrict__ out) {
    __shared__ float row[OUT_F];
    const int r = blockIdx.x, t = threadIdx.x;
    float v[16];
#pragma unroll
    for (int j = 0; j < 16; ++j) v[j] = 0.f;
#pragma unroll 1
    for (int sl = 0; sl < NSL; ++sl) {
        const uint4* p = reinterpret_cast<const uint4*>(
            pin + (size_t)sl * NROWS * OUT_F + (size_t)r * OUT_F + t * 16);
        float a[8], b[8];
        unpack8(p[0], a); unpack8(p[1], b);
#pragma unroll
        for (int j = 0; j < 8; ++j) { v[j] += a[j]; v[8 + j] += b[j]; }
    }
#pragma unroll
    for (int s = 0; s < 4; ++s) {
        const int h = 1 << s;
#pragma unroll
        for (int j = 0; j < 16; ++j)
            if (!(j & h)) { float a = v[j], b = v[j | h]; v[j] = a + b; v[j | h] = a - b; }
    }
#pragma unroll
    for (int q = 0; q < 4; ++q)
        reinterpret_cast<float4*>(row)[t * 4 + q] =
            make_float4(v[q * 4 + 0], v[q * 4 + 1], v[q * 4 + 2], v[q * 4 + 3]);
    __syncthreads();
#pragma unroll 1
    for (int s = 4; s < 13; ++s) {
        const int h = 1 << s;
        for (int p = t; p < OUT_F / 2; p += 512) {
            const int i = ((p >> s) << (s + 1)) | (p & (h - 1));
            const int j = i + h;
            float a = row[i], b = row[j];
            row[i] = a + b; row[j] = a - b;
        }
        __syncthreads();
    }
    const float4* svp = reinterpret_cast<const float4*>(SV);
    const float4* bip = reinterpret_cast<const float4*>(bias);
    float4* op = reinterpret_cast<float4*>(out + (size_t)r * OUT_F);
#pragma unroll
    for (int q = 0; q < 4; ++q) {
        float4 sv = svp[t * 4 + q], bi = bip[t * 4 + q], o;
        o.x = row[t * 16 + q * 4 + 0] * FWHT_SCALE * sv.x + bi.x;
        o.y = row[t * 16 + q * 4 + 1] * FWHT_SCALE * sv.y + bi.y;
        o.z = row[t * 16 + q * 4 + 2] * FWHT_SCALE * sv.z + bi.z;
        o.w = row[t * 16 + q * 4 + 3] * FWHT_SCALE * sv.w + bi.w;
        op[t * 4 + q] = o;
    }
}

// ================= FALLBACK PATH (round-3 proven, needs only 2MB ws) =========

__global__ __launch_bounds__(512) void k_pre_old(const float* __restrict__ in,
                                                 const float* __restrict__ scaleWH,
                                                 const float* __restrict__ SU,
                                                 unsigned short* __restrict__ xpre) {
    __shared__ float row[IN_F];
    const int r = blockIdx.x;
    const float4* src = reinterpret_cast<const float4*>(in + (size_t)r * IN_F);
    const float4* sc  = reinterpret_cast<const float4*>(scaleWH);
    const float4* su  = reinterpret_cast<const float4*>(SU);
    for (int c = threadIdx.x; c < IN_F / 4; c += 512) {
        float4 x = src[c], s = sc[c], u = su[c];
        row[c * 4 + 0] = x.x / s.x * u.x;
        row[c * 4 + 1] = x.y / s.y * u.y;
        row[c * 4 + 2] = x.z / s.z * u.z;
        row[c * 4 + 3] = x.w / s.w * u.w;
    }
    __syncthreads();
#pragma unroll 1
    for (int s = 0; s < 13; ++s) {
        const int h = 1 << s;
        for (int p = threadIdx.x; p < IN_F / 2; p += 512) {
            const int i = ((p >> s) << (s + 1)) | (p & (h - 1));
            const int j = i + h;
            float a = row[i], b = row[j];
            row[i] = a + b; row[j] = a - b;
        }
        __syncthreads();
    }
    uint4* dst = reinterpret_cast<uint4*>(xpre + (size_t)r * IN_F);
    for (int c = threadIdx.x; c < IN_F / 8; c += 512) {
        unsigned int w[4];
#pragma unroll
        for (int q = 0; q < 4; ++q) {
            unsigned int lo = f2bf(row[c * 8 + 2 * q]     * FWHT_SCALE);
            unsigned int hi = f2bf(row[c * 8 + 2 * q + 1] * FWHT_SCALE);
            w[q] = lo | (hi << 16);
        }
        dst[c] = make_uint4(w[0], w[1], w[2], w[3]);
    }
}

#define NT_OLD 32
#define KC_OLD 64
__global__ __launch_bounds__(256) void k_gemm_old(const unsigned short* __restrict__ xpre,
                                                  const int* __restrict__ Qidxs,
                                                  const float* __restrict__ cb,
                                                  const float* __restrict__ wscale,
                                                  float* __restrict__ out1) {
    __shared__ __align__(16) unsigned short cbl[CB][8];
    __shared__ __align__(16) unsigned short Atile[NROWS][72];
    __shared__ __align__(16) unsigned short Bt[NT_OLD][72];
    const int tid = threadIdx.x;
    const float ws = wscale[0];
    for (int e = tid; e < CB * 8; e += 256) cbl[e >> 3][e & 7] = f2bf(cb[e] * ws);
    const int n0 = blockIdx.x * NT_OLD;
    const int wave = tid >> 6, lane = tid & 63;
    const int lrow = lane & 15, lk8 = lane >> 4;
    f32x4 acc[2][2];
#pragma unroll
    for (int mt = 0; mt < 2; ++mt)
#pragma unroll
        for (int nt = 0; nt < 2; ++nt) acc[mt][nt] = (f32x4){0.f, 0.f, 0.f, 0.f};
    const int* qrow = Qidxs + (size_t)n0 * (IN_F / 8);
    const int bn = tid >> 3, bslot = tid & 7;
    __syncthreads();
    for (int kc = 0; kc < IN_F; kc += KC_OLD) {
#pragma unroll
        for (int it = 0; it < 4; ++it) {
            const int c = tid + it * 256;
            const int rowi = c >> 3, col8 = c & 7;
            uint4 v = *reinterpret_cast<const uint4*>(xpre + (size_t)rowi * IN_F + kc + col8 * 8);
            *reinterpret_cast<uint4*>(&Atile[rowi][col8 * 8]) = v;
        }
        {
            const int idx = qrow[(size_t)bn * (IN_F / 8) + (kc >> 3) + bslot];
            uint4 w = *reinterpret_cast<const uint4*>(&cbl[idx][0]);
            *reinterpret_cast<uint4*>(&Bt[bn][bslot * 8]) = w;
        }
        __syncthreads();
#pragma unroll
        for (int kk = 0; kk < KC_OLD; kk += 32) {
            bf8 afrag[2], bfrag[2];
#pragma unroll
            for (int mt = 0; mt < 2; ++mt)
                afrag[mt] = *reinterpret_cast<const bf8*>(&Atile[wave * 32 + mt * 16 + lrow][kk + lk8 * 8]);
#pragma unroll
            for (int nt = 0; nt < 2; ++nt)
                bfrag[nt] = *reinterpret_cast<const bf8*>(&Bt[nt * 16 + lrow][kk + lk8 * 8]);
#pragma unroll
            for (int mt = 0; mt < 2; ++mt)
#pragma unroll
                for (int nt = 0; nt < 2; ++nt)
                    acc[mt][nt] = __builtin_amdgcn_mfma_f32_16x16x32_bf16(
                        afrag[mt], bfrag[nt], acc[mt][nt], 0, 0, 0);
        }
        __syncthreads();
    }
    const int m0 = wave * 32;
#pragma unroll
    for (int mt = 0; mt < 2; ++mt)
#pragma unroll
        for (int nt = 0; nt < 2; ++nt)
#pragma unroll
            for (int r = 0; r < 4; ++r) {
                const int row = m0 + mt * 16 + lk8 * 4 + r;
                const int col = n0 + nt * 16 + lrow;
                out1[(size_t)row * OUT_F + col] = acc[mt][nt][r];
            }
}

__global__ __launch_bounds__(512) void k_post_old(float* __restrict__ io,
                                                  const float* __restrict__ SV,
                                                  const float* __restrict__ bias) {
    __shared__ float row[OUT_F];
    const int r = blockIdx.x;
    float4* rp = reinterpret_cast<float4*>(io + (size_t)r * OUT_F);
    for (int c = threadIdx.x; c < OUT_F / 4; c += 512) {
        float4 v = rp[c];
        row[c * 4 + 0] = v.x; row[c * 4 + 1] = v.y;
        row[c * 4 + 2] = v.z; row[c * 4 + 3] = v.w;
    }
    __syncthreads();
#pragma unroll 1
    for (int s = 0; s < 13; ++s) {
        const int h = 1 << s;
        for (int p = threadIdx.x; p < OUT_F / 2; p += 512) {
            const int i = ((p >> s) << (s + 1)) | (p & (h - 1));
            const int j = i + h;
            float a = row[i], b = row[j];
            row[i] = a + b; row[j] = a - b;
        }
        __syncthreads();
    }
    const float4* svp = reinterpret_cast<const float4*>(SV);
    const float4* bip = reinterpret_cast<const float4*>(bias);
    for (int c = threadIdx.x; c < OUT_F / 4; c += 512) {
        float4 sv = svp[c], bi = bip[c], o;
        o.x = row[c * 4 + 0] * FWHT_SCALE * sv.x + bi.x;
        o.y = row[c * 4 + 1] * FWHT_SCALE * sv.y + bi.y;
        o.z = row[c * 4 + 2] * FWHT_SCALE * sv.z + bi.z;
        o.w = row[c * 4 + 3] * FWHT_SCALE * sv.w + bi.w;
        rp[c] = o;
    }
}

extern "C" void kernel_launch(void* const* d_in, const int* in_sizes, int n_in,
                              void* d_out, int out_size, void* d_ws, size_t ws_size,
                              hipStream_t stream) {
    const float* in      = (const float*)d_in[0];
    const int*   Qidxs   = (const int*)d_in[1];
    const float* cb      = (const float*)d_in[2];
    const float* scaleWH = (const float*)d_in[3];
    const float* SU      = (const float*)d_in[4];
    const float* SV      = (const float*)d_in[5];
    const float* wscale  = (const float*)d_in[6];
    const float* bias    = (const float*)d_in[7];
    float* out = (float*)d_out;

    unsigned short* xpre = (unsigned short*)d_ws;                     // 2 MB
    const size_t XPRE_B = (size_t)NROWS * IN_F * 2;
    const size_t NEED   = XPRE_B + (size_t)NSL * NROWS * OUT_F * 2;   // 18 MB

    if (ws_size >= NEED) {
        unsigned short* parts = (unsigned short*)((char*)d_ws + XPRE_B);
        k_pre_new<<<NROWS, 512, 0, stream>>>(in, scaleWH, SU, xpre);
        k_gemm_new<<<dim3(OUT_F / 128, NSL), 256, 0, stream>>>(xpre, Qidxs, cb, wscale, parts);
        k_post_new<<<NROWS, 512, 0, stream>>>(parts, SV, bias, out);
    } else {
        k_pre_old<<<NROWS, 512, 0, stream>>>(in, scaleWH, SU, xpre);
        k_gemm_old<<<OUT_F / NT_OLD, 256, 0, stream>>>(xpre, Qidxs, cb, wscale, out);
        k_post_old<<<NROWS, 512, 0, stream>>>(out, SV, bias);
    }
}

// Round 5
// 67.766 us; speedup vs baseline: 1.6767x; 1.0216x over previous
//
#include <hip/hip_runtime.h>
#include <hip/hip_bf16.h>

#define IN_F 8192
#define OUT_F 8192
#define NROWS 128
#define CB 256
#define NSL 8                  // split-K slices
#define KSLICE (IN_F / NSL)    // 1024
#define KC 64                  // k-chunk staged per iteration
#define NTB 64                 // n-tile per block

using bf8   = __attribute__((ext_vector_type(8))) short;  // 8 bf16 (4 VGPRs)
using f32x4 = __attribute__((ext_vector_type(4))) float;  // 4 fp32 accum

typedef const __attribute__((address_space(1))) void* as1cv;
typedef __attribute__((address_space(3))) void* as3v;

__device__ inline float bf2f(unsigned int u) {
    union { unsigned int i; float f; } v; v.i = u << 16; return v.f;
}
__device__ inline unsigned short f2bf(float f) {
    __hip_bfloat16 h = __float2bfloat16(f);
    return *reinterpret_cast<unsigned short*>(&h);
}
__device__ inline void unpack8(uint4 v, float* f) {
    f[0] = bf2f(v.x & 0xffffu); f[1] = bf2f(v.x >> 16);
    f[2] = bf2f(v.y & 0xffffu); f[3] = bf2f(v.y >> 16);
    f[4] = bf2f(v.z & 0xffffu); f[5] = bf2f(v.z >> 16);
    f[6] = bf2f(v.w & 0xffffu); f[7] = bf2f(v.w >> 16);
}

#define FWHT_SCALE 0.011048543456039806f  // 1/sqrt(8192)

// 3-level in-register FWHT-8192: 256 threads x 32 elems.
// v[] starts as elements i = t*32 + j (bits 0-4 local). Levels: bits 0-4
// (in-reg), bits 5-8 (after exch 1), bits 9-12 (after exch 2); exch 3
// returns to linear so loads/stores stay coalesced. lds = float[8224].
#define FWHT_STAGES(LOJ, HIJ)                                             \
    _Pragma("unroll")                                                     \
    for (int hb = (LOJ); hb < (HIJ); ++hb) {                              \
        const int h = 1 << hb;                                            \
        _Pragma("unroll")                                                 \
        for (int j = 0; j < 32; ++j)                                      \
            if (!(j & h)) {                                               \
                float a = v[j], b = v[j | h];                             \
                v[j] = a + b; v[j | h] = a - b;                           \
            }                                                             \
    }

__device__ inline void fwht8192(float* v, float* lds, int t) {
    // level A: bits 0-4
    FWHT_STAGES(0, 5)
    // exch 1: L1[o][u] at o*257+u  (i = u*32+o; writer: o=j, u=t)
#pragma unroll
    for (int j = 0; j < 32; ++j) lds[j * 257 + t] = v[j];
    __syncthreads();
    {
        const int o = t & 31, uh = t >> 5;
        const int base = o * 257 + uh * 32;
#pragma unroll
        for (int k = 0; k < 32; ++k) v[k] = lds[base + k];   // u = uh*32+k
    }
    // level B: bits 5-8 (= u&15 = k&15; two independent halves k<16, k>=16)
    FWHT_STAGES(0, 4)
    __syncthreads();
    // exch 2: L2[o][m][w] at o*257 + m*16 + w  (m = u&15, w = u>>4)
    {
        const int o = t & 31, uh = t >> 5;
#pragma unroll
        for (int k = 0; k < 32; ++k)
            lds[o * 257 + (k & 15) * 16 + uh * 2 + (k >> 4)] = v[k];
    }
    __syncthreads();
    {
        const int o = t & 31, mh = t >> 5;
#pragma unroll
        for (int h2 = 0; h2 < 2; ++h2)
#pragma unroll
            for (int w = 0; w < 16; ++w)
                v[h2 * 16 + w] = lds[o * 257 + (mh * 2 + h2) * 16 + w];
    }
    // level C: bits 9-12 (= w), two halves h2
    FWHT_STAGES(0, 4)
    __syncthreads();
    // exch 3: back to linear i = w*512 + M*32 + o, XOR-quad swizzle
    {
        const int o = t & 31, mh = t >> 5;
#pragma unroll
        for (int h2 = 0; h2 < 2; ++h2) {
            const int M = 2 * mh + h2;
#pragma unroll
            for (int w = 0; w < 16; ++w) {
                const int i = w * 512 + M * 32 + o;
                const int q2 = (i >> 2) ^ (M & 7);
                lds[q2 * 4 + (o & 3)] = v[h2 * 16 + w];
            }
        }
    }
    __syncthreads();
#pragma unroll
    for (int j4 = 0; j4 < 8; ++j4) {
        const int q2 = (t * 8 + j4) ^ (t & 7);
        const float4 f = *reinterpret_cast<const float4*>(&lds[q2 * 4]);
        v[j4 * 4 + 0] = f.x; v[j4 * 4 + 1] = f.y;
        v[j4 * 4 + 2] = f.z; v[j4 * 4 + 3] = f.w;
    }
}

// ---- Kernel A: xpre = fwht(input/scaleWH*SU)  [bf16 out] ----
__global__ __launch_bounds__(256) void k_pre2(const float* __restrict__ in,
                                              const float* __restrict__ scaleWH,
                                              const float* __restrict__ SU,
                                              unsigned short* __restrict__ xpre) {
    __shared__ float lds[8224];
    const int r = blockIdx.x, t = threadIdx.x;
    float v[32];
    const float4* xp = reinterpret_cast<const float4*>(in + (size_t)r * IN_F);
    const float4* sp = reinterpret_cast<const float4*>(scaleWH);
    const float4* up = reinterpret_cast<const float4*>(SU);
#pragma unroll
    for (int q = 0; q < 8; ++q) {
        float4 x = xp[t * 8 + q], s = sp[t * 8 + q], u = up[t * 8 + q];
        v[q * 4 + 0] = x.x / s.x * u.x;
        v[q * 4 + 1] = x.y / s.y * u.y;
        v[q * 4 + 2] = x.z / s.z * u.z;
        v[q * 4 + 3] = x.w / s.w * u.w;
    }
    fwht8192(v, lds, t);
    uint4* dst = reinterpret_cast<uint4*>(xpre + (size_t)r * IN_F);
#pragma unroll
    for (int q = 0; q < 4; ++q) {
        unsigned int w[4];
#pragma unroll
        for (int p = 0; p < 4; ++p) {
            unsigned int lo = f2bf(v[q * 8 + 2 * p]     * FWHT_SCALE);
            unsigned int hi = f2bf(v[q * 8 + 2 * p + 1] * FWHT_SCALE);
            w[p] = lo | (hi << 16);
        }
        dst[t * 4 + q] = make_uint4(w[0], w[1], w[2], w[3]);
    }
}

// ---- Kernel B: bf16 partial GEMM slices ----
// grid (128, NSL); 256 thr = 4 waves (2 wave-rows x 2 wave-cols); tile 128x64.
// Qidxs register-prefetched one K-iteration ahead; A double-buffered via
// global_load_lds (linear LDS dest, pre-swizzled global source).
__global__ __launch_bounds__(256, 4) void k_gemm2(
        const unsigned short* __restrict__ xpre,
        const int* __restrict__ Qidxs,
        const float* __restrict__ cb,
        const float* __restrict__ wscale,
        unsigned short* __restrict__ pout) {
    __shared__ __align__(16) unsigned short cbl[CB][8];
    __shared__ __align__(16) unsigned short At[2][NROWS * KC];   // 2 x 16KB
    const int tid = threadIdx.x;
    const int wave = tid >> 6, lane = tid & 63;
    const int wr = wave >> 1, wc = wave & 1;
    const int lr = lane & 15, lk8 = lane >> 4;
    const int row_in = lane >> 3, slot = lane & 7;
    const int n0 = blockIdx.x * NTB;
    const int ks0 = blockIdx.y * KSLICE;
    const int QC = IN_F / 8;

    auto stage = [&](int buf, int kc) {
#pragma unroll
        for (int i = 0; i < 4; ++i) {
            const int srow = wave * 32 + i * 8 + row_in;
            const unsigned short* g = xpre + (size_t)srow * IN_F + ks0 + kc
                                      + ((slot ^ row_in) << 3);
            as3v l = (as3v)(At[buf] + (wave * 32 + i * 8) * KC);
            __builtin_amdgcn_global_load_lds((as1cv)(const void*)g, l, 16, 0, 0);
        }
    };
    stage(0, 0);
    const float wsc = wscale[0];
    for (int e = tid; e < CB * 8; e += 256) cbl[e >> 3][e & 7] = f2bf(cb[e] * wsc);

    f32x4 acc[4][2];
#pragma unroll
    for (int mt = 0; mt < 4; ++mt)
#pragma unroll
        for (int nt = 0; nt < 2; ++nt) acc[mt][nt] = (f32x4){0.f, 0.f, 0.f, 0.f};

    const int* q0 = Qidxs + (size_t)(n0 + wc * 32 + lr) * QC + ks0 / 8;
    int ic[2][2], nx[2][2];
    ic[0][0] = q0[lk8];           ic[0][1] = q0[4 + lk8];
    ic[1][0] = q0[16 * QC + lk8]; ic[1][1] = q0[16 * QC + 4 + lk8];
    __syncthreads();

    int buf = 0;
#pragma unroll 1
    for (int it = 0; it < KSLICE / KC; ++it) {
        if (it + 1 < KSLICE / KC) {
            stage(buf ^ 1, (it + 1) * KC);
            const int c8 = (it + 1) * 8;
            nx[0][0] = q0[c8 + lk8];           nx[0][1] = q0[c8 + 4 + lk8];
            nx[1][0] = q0[16 * QC + c8 + lk8]; nx[1][1] = q0[16 * QC + c8 + 4 + lk8];
        }
        const char* Ab = (const char*)At[buf];
#pragma unroll
        for (int kkh = 0; kkh < 2; ++kkh) {
            bf8 bfr[2], afr[4];
            bfr[0] = *(const bf8*)&cbl[ic[0][kkh]][0];
            bfr[1] = *(const bf8*)&cbl[ic[1][kkh]][0];
            const int octx = (kkh * 4 + lk8) ^ (lr & 7);
#pragma unroll
            for (int mt = 0; mt < 4; ++mt) {
                const int rowm = wr * 64 + mt * 16 + lr;
                afr[mt] = *(const bf8*)(Ab + rowm * (KC * 2) + (octx << 4));
            }
#pragma unroll
            for (int mt = 0; mt < 4; ++mt)
#pragma unroll
                for (int nt = 0; nt < 2; ++nt)
                    acc[mt][nt] = __builtin_amdgcn_mfma_f32_16x16x32_bf16(
                        afr[mt], bfr[nt], acc[mt][nt], 0, 0, 0);
        }
        __syncthreads();
#pragma unroll
        for (int a2 = 0; a2 < 2; ++a2)
#pragma unroll
            for (int b2 = 0; b2 < 2; ++b2) ic[a2][b2] = nx[a2][b2];
        buf ^= 1;
    }
    // epilogue: C/D col=lane&15, row=(lane>>4)*4+reg; bf16 partial store
    unsigned short* ps = pout + (size_t)blockIdx.y * (NROWS * OUT_F);
#pragma unroll
    for (int mt = 0; mt < 4; ++mt) {
        const int row = wr * 64 + mt * 16 + lk8 * 4;
#pragma unroll
        for (int nt = 0; nt < 2; ++nt) {
            const int col = n0 + wc * 32 + nt * 16 + lr;
#pragma unroll
            for (int r2 = 0; r2 < 4; ++r2)
                ps[(size_t)(row + r2) * OUT_F + col] = f2bf(acc[mt][nt][r2]);
        }
    }
}

// ---- Kernel C: out = fwht(sum_slices)*SV + bias  [f32 out] ----
__global__ __launch_bounds__(256) void k_post2(const unsigned short* __restrict__ pin,
                                               const float* __restrict__ SV,
                                               const float* __restrict__ bias,
                                               float* __restrict__ out) {
    __shared__ float lds[8224];
    const int r = blockIdx.x, t = threadIdx.x;
    float v[32];
#pragma unroll
    for (int j = 0; j < 32; ++j) v[j] = 0.f;
#pragma unroll 1
    for (int sl = 0; sl < NSL; ++sl) {
        const uint4* p = reinterpret_cast<const uint4*>(
            pin + (size_t)sl * NROWS * OUT_F + (size_t)r * OUT_F + t * 32);
#pragma unroll
        for (int q = 0; q < 4; ++q) {
            float a[8];
            unpack8(p[q], a);
#pragma unroll
            for (int j = 0; j < 8; ++j) v[q * 8 + j] += a[j];
        }
    }
    fwht8192(v, lds, t);
    const float4* svp = reinterpret_cast<const float4*>(SV);
    const float4* bip = reinterpret_cast<const float4*>(bias);
    float4* op = reinterpret_cast<float4*>(out + (size_t)r * OUT_F);
#pragma unroll
    for (int q = 0; q < 8; ++q) {
        float4 sv = svp[t * 8 + q], bi = bip[t * 8 + q], o;
        o.x = v[q * 4 + 0] * FWHT_SCALE * sv.x + bi.x;
        o.y = v[q * 4 + 1] * FWHT_SCALE * sv.y + bi.y;
        o.z = v[q * 4 + 2] * FWHT_SCALE * sv.z + bi.z;
        o.w = v[q * 4 + 3] * FWHT_SCALE * sv.w + bi.w;
        op[t * 8 + q] = o;
    }
}

extern "C" void kernel_launch(void* const* d_in, const int* in_sizes, int n_in,
                              void* d_out, int out_size, void* d_ws, size_t ws_size,
                              hipStream_t stream) {
    const float* in      = (const float*)d_in[0];
    const int*   Qidxs   = (const int*)d_in[1];
    const float* cb      = (const float*)d_in[2];
    const float* scaleWH = (const float*)d_in[3];
    const float* SU      = (const float*)d_in[4];
    const float* SV      = (const float*)d_in[5];
    const float* wscale  = (const float*)d_in[6];
    const float* bias    = (const float*)d_in[7];
    float* out = (float*)d_out;

    unsigned short* xpre  = (unsigned short*)d_ws;                    // 2 MB
    unsigned short* parts = (unsigned short*)((char*)d_ws
                            + (size_t)NROWS * IN_F * 2);              // 16 MB

    k_pre2<<<NROWS, 256, 0, stream>>>(in, scaleWH, SU, xpre);
    k_gemm2<<<dim3(OUT_F / NTB, NSL), 256, 0, stream>>>(xpre, Qidxs, cb, wscale, parts);
    k_post2<<<NROWS, 256, 0, stream>>>(parts, SV, bias, out);
}